// Round 18
// baseline (255.260 us; speedup 1.0000x reference)
//
#include <hip/hip_runtime.h>
#include <stdint.h>

typedef unsigned int u32;
typedef _Float16 f16;
typedef __attribute__((ext_vector_type(16))) float    f32x16;
typedef __attribute__((ext_vector_type(4)))  float    f32x4;
typedef __attribute__((ext_vector_type(8)))  _Float16 f16x8;
typedef __attribute__((ext_vector_type(4)))  _Float16 f16x4;

#define DIM    1024
#define NROWS  8192
#define NLAYER 10

// ---------- weight packer: f32 W -> fragment-ordered f16 chunks, REPLICATED x2 ----------
// Stream (l, c32) occupies 128 KB: chunk kc at kc*1024 AND (kc+64)*1024.
// A phase-biased base + literal offsets 0..71 KB then never needs wrapping.
// Lane holds A-operand frag of v_mfma_f32_32x32x16_f16:
//   W[c32*32 + (lane&31)][kc*16 + (lane>>5)*8 + j], j=0..7  (16 B per lane)
__global__ __launch_bounds__(256) void pack_weights(const float* __restrict__ W0,
                                                    const float* __restrict__ Wh,
                                                    f16* __restrict__ Wp) {
    int g    = blockIdx.x * 4 + (threadIdx.x >> 6);   // wave id = chunk id, 20480 total
    int lane = threadIdx.x & 63;
    int l    = g >> 11;
    int c32  = (g >> 6) & 31;
    int kc   = g & 63;
    int n  = c32 * 32 + (lane & 31);
    int k  = kc * 16 + (lane >> 5) * 8;
    const float* src = (l == 0 ? W0 : Wh + (size_t)(l - 1) * DIM * DIM) + (size_t)n * DIM + k;
    float4 w0 = *(const float4*)src;
    float4 w1 = *(const float4*)(src + 4);
    f16x8 o;
    o[0] = (f16)w0.x; o[1] = (f16)w0.y; o[2] = (f16)w0.z; o[3] = (f16)w0.w;
    o[4] = (f16)w1.x; o[5] = (f16)w1.y; o[6] = (f16)w1.z; o[7] = (f16)w1.w;
    char* dst = (char*)Wp + (size_t)(l * 32 + c32) * 131072 + kc * 1024 + lane * 16;
    *(f16x8*)dst = o;
    *(f16x8*)(dst + 65536) = o;   // replica
}

// ---------- persistent row-local chain (r14 loop, phase-biased streams) ----------
// 256 blocks x 1024 threads (16 waves, 4/SIMD, 1 block/CU via 128 KB LDS).
// h[32][1024] f16 SINGLE buffer, fragment-linear, REPLICATED x2 in LDS
// (chunk kc at kc*1024 and +65536); in-place update with barrier (r11 pattern).
// Block phase = ((bid>>3)*2)&63 -> the 32 co-XCD blocks (XCD = bid&7) start
// their W/h streams at 32 DISTINCT chunks. Applied as a ONE-TIME base bias;
// the k-loop is r14's literal-offset unrolled code verbatim (VGPR 60, no wrap).
// Tests: co-XCD same-line L2 contention vs per-CU pull cap.
__global__ __launch_bounds__(1024, 4) void mono_chain(
        const float* __restrict__ x,
        const f16* __restrict__ Wp,
        const float* __restrict__ b0g,
        const float* __restrict__ bh,
        const float* __restrict__ Wout,
        const float* __restrict__ bout,
        float* __restrict__ out) {
    __shared__ char lds[131072];   // h + mirror

    const int tid  = threadIdx.x;
    const int lane = tid & 63;
    const int wid  = tid >> 6;        // 0..15
    const int r0   = blockIdx.x * 32;
    const int phase = (int)(((blockIdx.x >> 3) << 1) & 63);   // uniform -> SGPR

    // ---- stage x rows -> h (f32 -> f16, fragment-linear, both copies) ----
    {
        const float* xs = x + (size_t)r0 * DIM;
        #pragma unroll
        for (int it = 0; it < 8; ++it) {
            int f = it * 4096 + tid * 4;          // flat r*1024 + k
            float4 v = *(const float4*)(xs + f);
            f16x4 o;
            o.x = (f16)v.x; o.y = (f16)v.y; o.z = (f16)v.z; o.w = (f16)v.w;
            int r = f >> 10, k = f & 1023;
            int addr = (k >> 4) * 1024 + (r + ((k >> 3) & 1) * 32) * 16 + (k & 7) * 2;
            *(f16x4*)(lds + addr) = o;
            *(f16x4*)(lds + addr + 65536) = o;    // mirror
        }
    }
    __syncthreads();

    const char* hL = lds + phase * 1024 + lane * 16;   // phase-biased h stream

    for (int l = 0; l < NLAYER; ++l) {
        // phase-biased W streams (stream stride now 128 KB, layer stride 4 MB)
        const char* w0 = (const char*)Wp + (size_t)l * 4194304
                       + (size_t)(wid * 2) * 131072 + phase * 1024 + lane * 16;
        const char* w1 = w0 + 131072;

        f32x16 acc0 = (f32x16)(0.f), acc1 = (f32x16)(0.f);

        // prologue: W slots p=0..7 (depth-8 x 2 streams), h slots p=0..1
        f16x8 A0, A1, A2, A3, A4, A5, A6, A7;
        f16x8 B0, B1, B2, B3, B4, B5, B6, B7;
        f16x8 h0, h1;
        A0 = *(const f16x8*)(w0);          B0 = *(const f16x8*)(w1);
        A1 = *(const f16x8*)(w0 + 1024);   B1 = *(const f16x8*)(w1 + 1024);
        A2 = *(const f16x8*)(w0 + 2048);   B2 = *(const f16x8*)(w1 + 2048);
        A3 = *(const f16x8*)(w0 + 3072);   B3 = *(const f16x8*)(w1 + 3072);
        A4 = *(const f16x8*)(w0 + 4096);   B4 = *(const f16x8*)(w1 + 4096);
        A5 = *(const f16x8*)(w0 + 5120);   B5 = *(const f16x8*)(w1 + 5120);
        A6 = *(const f16x8*)(w0 + 6144);   B6 = *(const f16x8*)(w1 + 6144);
        A7 = *(const f16x8*)(w0 + 7168);   B7 = *(const f16x8*)(w1 + 7168);
        h0 = *(const f16x8*)(hL);
        h1 = *(const f16x8*)(hL + 1024);

        // r14 STEP verbatim: consume literal position p, refill p+8 (W) / p+2 (h).
        // Replication makes biased addresses valid for all literal p < 72.
#define STEP(QA, QB, HH, KW, KH)                                               \
        __builtin_amdgcn_s_setprio(1);                                         \
        acc0 = __builtin_amdgcn_mfma_f32_32x32x16_f16(QA, HH, acc0, 0, 0, 0);  \
        acc1 = __builtin_amdgcn_mfma_f32_32x32x16_f16(QB, HH, acc1, 0, 0, 0);  \
        __builtin_amdgcn_s_setprio(0);                                         \
        if ((KW) < 64) {                                                       \
            QA = *(const f16x8*)(w0 + (size_t)(KW) * 1024);                    \
            QB = *(const f16x8*)(w1 + (size_t)(KW) * 1024);                    \
        }                                                                      \
        if ((KH) < 64) HH = *(const f16x8*)(hL + (size_t)(KH) * 1024);

        #pragma unroll
        for (int T = 0; T < 8; ++T) {
            const int b = T * 8;
            STEP(A0, B0, h0, b + 8,  b + 2)   // consume p=b+0
            STEP(A1, B1, h1, b + 9,  b + 3)   // p=b+1
            STEP(A2, B2, h0, b + 10, b + 4)   // p=b+2
            STEP(A3, B3, h1, b + 11, b + 5)   // p=b+3
            STEP(A4, B4, h0, b + 12, b + 6)   // p=b+4
            STEP(A5, B5, h1, b + 13, b + 7)   // p=b+5
            STEP(A6, B6, h0, b + 14, b + 8)   // p=b+6
            STEP(A7, B7, h1, b + 15, b + 9)   // p=b+7
        }
#undef STEP

        __syncthreads();   // ALL waves' h reads done -> in-place overwrite safe

        // ---- epilogue: bias + sigmoid -> f16 in place (both copies) ----
        // D: row = lane&31; col = wid*64 + nf*32 + g2*8 + 4*(lane>>5) + j
        const float* bias = l ? (bh + (size_t)(l - 1) * DIM) : b0g;
        const int rD   = lane & 31;
        const int hsel = lane >> 5;
#define EPI(ACC, NF)                                                           \
        {                                                                      \
            _Pragma("unroll")                                                  \
            for (int g2 = 0; g2 < 4; ++g2) {                                   \
                int c = wid * 64 + (NF) * 32 + g2 * 8 + 4 * hsel;              \
                f32x4 bv = *(const f32x4*)(bias + c);                          \
                f16x4 o;                                                       \
                _Pragma("unroll")                                              \
                for (int j = 0; j < 4; ++j) {                                  \
                    float z = ACC[g2 * 4 + j] + bv[j];                         \
                    o[j] = (f16)(1.0f / (1.0f + __expf(-z)));                  \
                }                                                              \
                int ce = wid * 4 + (NF) * 2 + (g2 >> 1);                       \
                u32 a = (u32)(ce << 10)                                        \
                      + (u32)((rD + ((g2 & 1) << 5)) * 16 + hsel * 8);         \
                *(f16x4*)(lds + a) = o;                                        \
                *(f16x4*)(lds + a + 65536) = o;                                \
            }                                                                  \
        }
        EPI(acc0, 0)
        EPI(acc1, 1)
#undef EPI
        __syncthreads();   // h_next (both copies) complete before next layer
    }

    // ---- output gemv: 32 threads per row, 32 rows (reads base copy) ----
    {
        int row = tid >> 5;           // 0..31
        int seg = tid & 31;           // k in [seg*32, +32)
        float s = 0.f;
        #pragma unroll
        for (int i = 0; i < 4; ++i) {
            int k  = seg * 32 + i * 8;
            int kc = k >> 4;
            f16x8 h8 = *(const f16x8*)(lds + kc * 1024
                                          + (row + 32 * ((k >> 3) & 1)) * 16);
            const float* w = Wout + k;
            f32x4 w0 = *(const f32x4*)w;
            f32x4 w1 = *(const f32x4*)(w + 4);
            s += (float)h8[0] * w0[0] + (float)h8[1] * w0[1]
               + (float)h8[2] * w0[2] + (float)h8[3] * w0[3]
               + (float)h8[4] * w1[0] + (float)h8[5] * w1[1]
               + (float)h8[6] * w1[2] + (float)h8[7] * w1[3];
        }
        #pragma unroll
        for (int off2 = 16; off2 > 0; off2 >>= 1)
            s += __shfl_down(s, off2, 32);
        if (seg == 0) out[r0 + row] = s + bout[0];
    }
}

// ---------- launcher ----------
extern "C" void kernel_launch(void* const* d_in, const int* in_sizes, int n_in,
                              void* d_out, int out_size, void* d_ws, size_t ws_size,
                              hipStream_t stream) {
    const float* x    = (const float*)d_in[0];
    const float* W0   = (const float*)d_in[1];
    const float* b0   = (const float*)d_in[2];
    const float* Wh   = (const float*)d_in[3];
    const float* bh   = (const float*)d_in[4];
    const float* Wout = (const float*)d_in[5];
    const float* bout = (const float*)d_in[6];
    float* out = (float*)d_out;

    f16* Wp = (f16*)d_ws;   // 40 MB packed+replicated weights

    pack_weights<<<NLAYER * 32 * 64 / 4, 256, 0, stream>>>(W0, Wh, Wp);
    mono_chain<<<NROWS / 32, 1024, 0, stream>>>(x, Wp, b0, bh, Wout, bout, out);
}

// Round 19
// 239.353 us; speedup vs baseline: 1.0665x; 1.0665x over previous
//
#include <hip/hip_runtime.h>
#include <stdint.h>

typedef unsigned int u32;
typedef _Float16 f16;
typedef __attribute__((ext_vector_type(16))) float    f32x16;
typedef __attribute__((ext_vector_type(4)))  float    f32x4;
typedef __attribute__((ext_vector_type(8)))  _Float16 f16x8;
typedef __attribute__((ext_vector_type(4)))  _Float16 f16x4;

#define DIM    1024
#define NROWS  8192
#define NLAYER 10

// ---------- weight packer: f32 W -> MFMA-fragment-ordered f16 chunks ----------
// Chunk (l, c32, kc): 1 KB. Lane holds A-operand frag of v_mfma_f32_32x32x16_f16:
//   W[c32*32 + (lane&31)][kc*16 + (lane>>5)*8 + j], j=0..7  (16 B per lane)
__global__ __launch_bounds__(256) void pack_weights(const float* __restrict__ W0,
                                                    const float* __restrict__ Wh,
                                                    f16* __restrict__ Wp) {
    int g    = blockIdx.x * 4 + (threadIdx.x >> 6);   // wave id = chunk id, 20480 total
    int lane = threadIdx.x & 63;
    int l    = g >> 11;
    int c32  = (g >> 6) & 31;
    int kc   = g & 63;
    int n  = c32 * 32 + (lane & 31);
    int k  = kc * 16 + (lane >> 5) * 8;
    const float* src = (l == 0 ? W0 : Wh + (size_t)(l - 1) * DIM * DIM) + (size_t)n * DIM + k;
    float4 w0 = *(const float4*)src;
    float4 w1 = *(const float4*)(src + 4);
    f16x8 o;
    o[0] = (f16)w0.x; o[1] = (f16)w0.y; o[2] = (f16)w0.z; o[3] = (f16)w0.w;
    o[4] = (f16)w1.x; o[5] = (f16)w1.y; o[6] = (f16)w1.z; o[7] = (f16)w1.w;
    *(f16x8*)((char*)Wp + (size_t)g * 1024 + lane * 16) = o;
}

// ---------- persistent row-local chain: 10 layers + gemv (FINAL, r14/r17) ----------
// 256 blocks x 1024 threads (16 waves, 4/SIMD, 1 block/CU via 128 KB LDS).
// h[32][1024] f16 double-buffered, fragment-linear (k-loop ds_read lane-linear,
// conflict-free). Wave w: cols [w*64,+64) (W chunks 2w, 2w+1), 2 MFMA/kc.
//
// ROOFLINE NOTE (18-round evidence): per-layer ~23.5 us is the per-CU L2
// W-stream floor: 2 MB/CU/layer at ~85-90 GB/s/CU sustained pull. Invariant
// under prefetch depth 1/3/8 (r9/r10/r14), stream phase (r18), occupancy
// 1-8 blocks/CU (r1-r8), and both decompositions. Deeper pipelines do not
// survive hipcc (r13 spill, r15 asm crash, r16 spill); col-split exchange
// destroys L2 residency (r12); fp8 weights fail the 1.8e-3 threshold.
__global__ __launch_bounds__(1024, 4) void mono_chain(
        const float* __restrict__ x,
        const f16* __restrict__ Wp,
        const float* __restrict__ b0g,
        const float* __restrict__ bh,
        const float* __restrict__ Wout,
        const float* __restrict__ bout,
        float* __restrict__ out) {
    __shared__ char lds[2 * 65536];

    const int tid  = threadIdx.x;
    const int lane = tid & 63;
    const int wid  = tid >> 6;        // 0..15
    const int r0   = blockIdx.x * 32;

    // ---- stage x rows -> buf0 (f32 -> f16, fragment-linear) ----
    {
        const float* xs = x + (size_t)r0 * DIM;
        #pragma unroll
        for (int it = 0; it < 8; ++it) {
            int f = it * 4096 + tid * 4;          // flat r*1024 + k
            float4 v = *(const float4*)(xs + f);
            f16x4 o;
            o.x = (f16)v.x; o.y = (f16)v.y; o.z = (f16)v.z; o.w = (f16)v.w;
            int r = f >> 10, k = f & 1023;
            int addr = (k >> 4) * 1024 + (r + ((k >> 3) & 1) * 32) * 16 + (k & 7) * 2;
            *(f16x4*)(lds + addr) = o;
        }
    }
    __syncthreads();

    int curbuf = 0;
    for (int l = 0; l < NLAYER; ++l) {
        const char* hb = lds + curbuf * 65536;
        char*       hn = lds + (curbuf ^ 1) * 65536;
        const char* w0 = (const char*)Wp + (size_t)l * 2097152
                       + (size_t)(wid * 2) * 65536 + lane * 16;
        const char* w1 = w0 + 65536;
        const char* hL = hb + lane * 16;

        f32x16 acc0 = (f32x16)(0.f), acc1 = (f32x16)(0.f);

        // prologue: W slots kc=0..7 (depth-8 x 2 streams), h slots kc=0..1
        f16x8 A0, A1, A2, A3, A4, A5, A6, A7;
        f16x8 B0, B1, B2, B3, B4, B5, B6, B7;
        f16x8 h0, h1;
        A0 = *(const f16x8*)(w0);          B0 = *(const f16x8*)(w1);
        A1 = *(const f16x8*)(w0 + 1024);   B1 = *(const f16x8*)(w1 + 1024);
        A2 = *(const f16x8*)(w0 + 2048);   B2 = *(const f16x8*)(w1 + 2048);
        A3 = *(const f16x8*)(w0 + 3072);   B3 = *(const f16x8*)(w1 + 3072);
        A4 = *(const f16x8*)(w0 + 4096);   B4 = *(const f16x8*)(w1 + 4096);
        A5 = *(const f16x8*)(w0 + 5120);   B5 = *(const f16x8*)(w1 + 5120);
        A6 = *(const f16x8*)(w0 + 6144);   B6 = *(const f16x8*)(w1 + 6144);
        A7 = *(const f16x8*)(w0 + 7168);   B7 = *(const f16x8*)(w1 + 7168);
        h0 = *(const f16x8*)(hL);
        h1 = *(const f16x8*)(hL + 1024);

        // STEP consumes (QA,QB,HH) for kc, refills QA/QB with kc=KW (depth-8)
        // and HH with kc=KH (depth-2). Compile-time guards drop OOB refills
        // in the final group (T fully unrolled => all offsets are literals).
#define STEP(QA, QB, HH, KW, KH)                                               \
        __builtin_amdgcn_s_setprio(1);                                         \
        acc0 = __builtin_amdgcn_mfma_f32_32x32x16_f16(QA, HH, acc0, 0, 0, 0);  \
        acc1 = __builtin_amdgcn_mfma_f32_32x32x16_f16(QB, HH, acc1, 0, 0, 0);  \
        __builtin_amdgcn_s_setprio(0);                                         \
        if ((KW) < 64) {                                                       \
            QA = *(const f16x8*)(w0 + (size_t)(KW) * 1024);                    \
            QB = *(const f16x8*)(w1 + (size_t)(KW) * 1024);                    \
        }                                                                      \
        if ((KH) < 64) HH = *(const f16x8*)(hL + (size_t)(KH) * 1024);

        #pragma unroll
        for (int T = 0; T < 8; ++T) {
            const int b = T * 8;
            STEP(A0, B0, h0, b + 8,  b + 2)   // consume kc=b+0
            STEP(A1, B1, h1, b + 9,  b + 3)   // kc=b+1
            STEP(A2, B2, h0, b + 10, b + 4)   // kc=b+2
            STEP(A3, B3, h1, b + 11, b + 5)   // kc=b+3
            STEP(A4, B4, h0, b + 12, b + 6)   // kc=b+4
            STEP(A5, B5, h1, b + 13, b + 7)   // kc=b+5
            STEP(A6, B6, h0, b + 14, b + 8)   // kc=b+6
            STEP(A7, B7, h1, b + 15, b + 9)   // kc=b+7
        }
#undef STEP

        // ---- epilogue: bias + sigmoid -> f16 into h_next ----
        // D: row = lane&31; col = wid*64 + nf*32 + g2*8 + 4*(lane>>5) + j
        const float* bias = l ? (bh + (size_t)(l - 1) * DIM) : b0g;
        const int rD   = lane & 31;
        const int hsel = lane >> 5;
#define EPI(ACC, NF)                                                           \
        {                                                                      \
            _Pragma("unroll")                                                  \
            for (int g2 = 0; g2 < 4; ++g2) {                                   \
                int c = wid * 64 + (NF) * 32 + g2 * 8 + 4 * hsel;              \
                f32x4 bv = *(const f32x4*)(bias + c);                          \
                f16x4 o;                                                       \
                _Pragma("unroll")                                              \
                for (int j = 0; j < 4; ++j) {                                  \
                    float z = ACC[g2 * 4 + j] + bv[j];                         \
                    o[j] = (f16)(1.0f / (1.0f + __expf(-z)));                  \
                }                                                              \
                int ce = wid * 4 + (NF) * 2 + (g2 >> 1);                       \
                *(f16x4*)(hn + (ce << 10)                                      \
                             + (rD + ((g2 & 1) << 5)) * 16 + hsel * 8) = o;    \
            }                                                                  \
        }
        EPI(acc0, 0)
        EPI(acc1, 1)
#undef EPI
        __syncthreads();   // h_next complete before next layer's reads
        curbuf ^= 1;
    }

    // ---- output gemv: 32 threads per row, 32 rows ----
    {
        const char* hf = lds + curbuf * 65536;
        int row = tid >> 5;           // 0..31
        int seg = tid & 31;           // k in [seg*32, +32)
        float s = 0.f;
        #pragma unroll
        for (int i = 0; i < 4; ++i) {
            int k  = seg * 32 + i * 8;
            int kc = k >> 4;
            f16x8 h8 = *(const f16x8*)(hf + kc * 1024
                                          + (row + 32 * ((k >> 3) & 1)) * 16);
            const float* w = Wout + k;
            f32x4 w0 = *(const f32x4*)w;
            f32x4 w1 = *(const f32x4*)(w + 4);
            s += (float)h8[0] * w0[0] + (float)h8[1] * w0[1]
               + (float)h8[2] * w0[2] + (float)h8[3] * w0[3]
               + (float)h8[4] * w1[0] + (float)h8[5] * w1[1]
               + (float)h8[6] * w1[2] + (float)h8[7] * w1[3];
        }
        #pragma unroll
        for (int off2 = 16; off2 > 0; off2 >>= 1)
            s += __shfl_down(s, off2, 32);
        if (seg == 0) out[r0 + row] = s + bout[0];
    }
}

// ---------- launcher ----------
extern "C" void kernel_launch(void* const* d_in, const int* in_sizes, int n_in,
                              void* d_out, int out_size, void* d_ws, size_t ws_size,
                              hipStream_t stream) {
    const float* x    = (const float*)d_in[0];
    const float* W0   = (const float*)d_in[1];
    const float* b0   = (const float*)d_in[2];
    const float* Wh   = (const float*)d_in[3];
    const float* bh   = (const float*)d_in[4];
    const float* Wout = (const float*)d_in[5];
    const float* bout = (const float*)d_in[6];
    float* out = (float*)d_out;

    f16* Wp = (f16*)d_ws;   // 20 MB packed weights

    pack_weights<<<NLAYER * 32 * 64 / 4, 256, 0, stream>>>(W0, Wh, Wp);
    mono_chain<<<NROWS / 32, 1024, 0, stream>>>(x, Wp, b0, bh, Wout, bout, out);
}